// Round 9
// baseline (156.571 us; speedup 1.0000x reference)
//
#include <hip/hip_runtime.h>

#define Ssz 2048
#define Dd  128
#define Hh  8
#define Bb  2
#define HDp 1024

typedef unsigned short u16;
typedef unsigned int   u32;

typedef __attribute__((ext_vector_type(8))) short bf16x8;   // 8 bf16 = 4 VGPRs
typedef __attribute__((ext_vector_type(4))) float f32x4;    // C/D frag

__device__ __forceinline__ float bflo(u32 w) { return __uint_as_float(w << 16); }
__device__ __forceinline__ u16 f2bf(float f) {
    u32 x = __float_as_uint(f);
    u32 r = x + 0x7fffu + ((x >> 16) & 1u);
    return (u16)(r >> 16);
}
__device__ __forceinline__ u32 pack2(float a, float b) {
    return (u32)f2bf(a) | ((u32)f2bf(b) << 16);
}

// ---------------- W prep: transpose W[128][1024] -> W^T bf16 [1024][128] -----
// Done once per W (grid.y = which); removes scalar LDS transposes from the
// 3072-block proj kernel.
__global__ __launch_bounds__(256, 2)
void wprep_kernel(const float* __restrict__ Wq, const float* __restrict__ Wk,
                  const float* __restrict__ Wv, u16* __restrict__ Wtp)
{
    __shared__ float Ls[128][68];
    const int which = blockIdx.y;
    const float* W = (which == 0) ? Wq : (which == 1) ? Wk : Wv;
    u16* dst = Wtp + (size_t)which * (HDp * Dd);
    const int n0 = blockIdx.x << 6;
    const int t = threadIdx.x;

    {   // load 128 k-rows x 64 n-cols, f32
        const int k = t >> 1, seg = t & 1;
        const float* src = W + (size_t)k * HDp + n0 + seg * 32;
        #pragma unroll
        for (int u = 0; u < 8; ++u) {
            float4 a = *(const float4*)(src + u * 4);
            *(float4*)&Ls[k][seg * 32 + u * 4] = a;
        }
    }
    __syncthreads();
    {   // write W^T rows: n-major, k contiguous, bf16
        const int nloc = t & 63, kseg = t >> 6;       // kseg 0..3 -> 32 k each
        u16* o = dst + (size_t)(n0 + nloc) * Dd + kseg * 32;
        #pragma unroll
        for (int u = 0; u < 4; ++u) {
            const int k = kseg * 32 + u * 8;
            uint4 wv = make_uint4(pack2(Ls[k+0][nloc], Ls[k+1][nloc]),
                                  pack2(Ls[k+2][nloc], Ls[k+3][nloc]),
                                  pack2(Ls[k+4][nloc], Ls[k+5][nloc]),
                                  pack2(Ls[k+6][nloc], Ls[k+7][nloc]));
            *(uint4*)(o + u * 8) = wv;
        }
    }
}

// ---------------- Projection (MFMA): [4096x128] @ [128x3072] ----------------
// Q/K: operand-swapped MFMA (D[nc][ss]) -> packed uint2 row-major stores.
// V:  normal orientation -> packed uint2 d-major stores ([b,h,d,s]).
__global__ __launch_bounds__(256, 4)
void proj_kernel(const float* __restrict__ q, const float* __restrict__ k,
                 const float* __restrict__ v, const u16* __restrict__ Wtp,
                 u16* __restrict__ Qp, u16* __restrict__ Kp, u16* __restrict__ VpT)
{
    __shared__ __align__(16) u16 Xs[64][136];
    __shared__ __align__(16) u16 Wt[64][136];

    const int t  = threadIdx.x;
    const int m0 = blockIdx.x << 6;
    const int n0 = blockIdx.y << 6;
    const int which = n0 >> 10;                 // 0=Q,1=K,2=V
    const float* x = (which == 0) ? q : (which == 1) ? k : v;
    const int nc0 = n0 & 1023;

    {   // stage X (64x128) f32->bf16 rows
        const int row = t >> 2, seg = t & 3;
        const float* src = x + (size_t)(m0 + row) * Dd + seg * 32;
        u16* dl = &Xs[row][seg * 32];
        #pragma unroll
        for (int u = 0; u < 4; ++u) {
            float4 a = *(const float4*)(src + u * 8);
            float4 b = *(const float4*)(src + u * 8 + 4);
            *(uint4*)(dl + u * 8) = make_uint4(pack2(a.x, a.y), pack2(a.z, a.w),
                                               pack2(b.x, b.y), pack2(b.z, b.w));
        }
    }
    {   // stage W^T tile (64 n-rows x 128 k) — raw bf16 copy from prep
        const int nr = t >> 2, seg = t & 3;
        const u16* src = Wtp + (size_t)which * (HDp * Dd)
                       + (size_t)(nc0 + nr) * Dd + seg * 32;
        u16* dl = &Wt[nr][seg * 32];
        #pragma unroll
        for (int u = 0; u < 4; ++u)
            *(uint4*)(dl + u * 8) = *(const uint4*)(src + u * 8);
    }
    __syncthreads();

    const int lane = t & 63, w = t >> 6;
    const int L15 = lane & 15, quad = lane >> 4;

    f32x4 acc[4] = {};
    if (which < 2) {
        // A = Wt rows (nc), B = Xs rows (ss): D[nc][ss]
        #pragma unroll
        for (int ks = 0; ks < 4; ++ks) {
            bf16x8 a = *(const bf16x8*)&Wt[16 * w + L15][ks * 32 + quad * 8];
            #pragma unroll
            for (int nt = 0; nt < 4; ++nt) {
                bf16x8 b = *(const bf16x8*)&Xs[nt * 16 + L15][ks * 32 + quad * 8];
                acc[nt] = __builtin_amdgcn_mfma_f32_16x16x32_bf16(a, b, acc[nt], 0, 0, 0);
            }
        }
        u16* dst = (which == 0) ? Qp : Kp;
        #pragma unroll
        for (int nt = 0; nt < 4; ++nt) {
            const int ss   = m0 + nt * 16 + L15;
            const int bb   = ss >> 11, sloc = ss & 2047;
            const int nc   = nc0 + 16 * w + quad * 4;
            const int hh   = nc >> 7, dd = nc & 127;
            u16* o = dst + ((size_t)((bb * Hh + hh) * Ssz + sloc)) * Dd + dd;
            *(uint2*)o = make_uint2(pack2(acc[nt][0], acc[nt][1]),
                                    pack2(acc[nt][2], acc[nt][3]));
        }
    } else {
        // A = Xs rows (ss), B = Wt rows (nc): D[ss][nc]
        #pragma unroll
        for (int ks = 0; ks < 4; ++ks) {
            bf16x8 a = *(const bf16x8*)&Xs[16 * w + L15][ks * 32 + quad * 8];
            #pragma unroll
            for (int nt = 0; nt < 4; ++nt) {
                bf16x8 b = *(const bf16x8*)&Wt[nt * 16 + L15][ks * 32 + quad * 8];
                acc[nt] = __builtin_amdgcn_mfma_f32_16x16x32_bf16(a, b, acc[nt], 0, 0, 0);
            }
        }
        #pragma unroll
        for (int nt = 0; nt < 4; ++nt) {
            const int nc   = nc0 + nt * 16 + L15;
            const int hh   = nc >> 7, dd = nc & 127;
            const int ss   = m0 + 16 * w + quad * 4;
            const int bb   = ss >> 11, sloc = ss & 2047;
            u16* o = VpT + ((size_t)((bb * Hh + hh) * Dd + dd)) * Ssz + sloc;
            *(uint2*)o = make_uint2(pack2(acc[nt][0], acc[nt][1]),
                                    pack2(acc[nt][2], acc[nt][3]));
        }
    }
}

// ---------------- Windowed flash attention (MFMA, 64-key chunks) -------------
// Window: j in [i-511, i-1]; row 0 -> V[0]. XCD swizzle: each XCD owns 2 (b,h)
// combos so the shared K/V window stays L2-resident. K/V double-buffered
// through registers (prefetch chunk j+1 while computing chunk j).
__global__ __launch_bounds__(256, 2)
void attn_kernel(const u16* __restrict__ Qp, const u16* __restrict__ Kp,
                 const u16* __restrict__ VpT, const float* __restrict__ emb,
                 float* __restrict__ out)
{
    __shared__ __align__(16) u16 Qls[64][136];
    __shared__ __align__(16) u16 Ks[64][136];
    __shared__ __align__(16) u16 Vt[128][72];
    __shared__ __align__(16) u16 Ps[64][72];
    __shared__ float embs[512];

    const int t = threadIdx.x;
    const int f = blockIdx.x;                 // 0..511
    const int xcd = f & 7, uu = f >> 3;
    const int g  = xcd + ((uu >> 5) << 3);    // combo 0..15 = b*8+h
    const int it = uu & 31;
    const int b = g >> 3, h = g & 7;
    const int i0 = it << 6;

    const size_t hoff = (size_t)(b * Hh + h) * Ssz * Dd;
    const u16* Qh = Qp + hoff;
    const u16* Kh = Kp + hoff;
    const u16* Vh = VpT + hoff;               // d-major [d][s]

    embs[t] = emb[t]; embs[t + 256] = emb[t + 256];

    {   // stage Q rows (raw bf16 copy, 64x128)
        const int row = t >> 2, seg = t & 3;
        const u16* src = Qh + (size_t)(i0 + row) * Dd + seg * 32;
        u16* dl = &Qls[row][seg * 32];
        #pragma unroll
        for (int u = 0; u < 4; ++u)
            *(uint4*)(dl + u * 8) = *(const uint4*)(src + u * 8);
    }
    __syncthreads();

    const int lane = t & 63, w = t >> 6;
    const int L15 = lane & 15, quad = lane >> 4;

    bf16x8 qf[4];
    #pragma unroll
    for (int ks = 0; ks < 4; ++ks)
        qf[ks] = *(const bf16x8*)&Qls[16 * w + L15][ks * 32 + quad * 8];

    const float scale = 0.08838834764831845f;
    float m_r[4], l_r[4];
    #pragma unroll
    for (int r = 0; r < 4; ++r) { m_r[r] = -1e30f; l_r[r] = 0.f; }
    f32x4 acc_o[8] = {};

    const int kjr = t >> 2, kseg = t & 3;     // K: row, col-seg (32 each)
    const int vdr = t >> 1, vseg = t & 1;     // V: d-row, col-seg (32 each)
    uint4 kr[4], vr[4];
    auto loadKV = [&](int j0) {
        const u16* ksrc = Kh + (size_t)(j0 + kjr) * Dd + kseg * 32;
        #pragma unroll
        for (int u = 0; u < 4; ++u) kr[u] = *(const uint4*)(ksrc + u * 8);
        const u16* vsrc = Vh + (size_t)vdr * Ssz + j0 + vseg * 32;
        #pragma unroll
        for (int u = 0; u < 4; ++u) vr[u] = *(const uint4*)(vsrc + u * 8);
    };

    const int cbeg = (i0 >= 512) ? (i0 - 512) : 0;
    loadKV(cbeg);
    for (int j0 = cbeg; j0 <= i0; j0 += 64) {
        __syncthreads();                       // previous chunk fully consumed
        {   // regs -> LDS
            u16* kd = &Ks[kjr][kseg * 32];
            #pragma unroll
            for (int u = 0; u < 4; ++u) *(uint4*)(kd + u * 8) = kr[u];
            u16* vd = &Vt[vdr][vseg * 32];
            #pragma unroll
            for (int u = 0; u < 4; ++u) *(uint4*)(vd + u * 8) = vr[u];
        }
        __syncthreads();
        if (j0 + 64 <= i0) loadKV(j0 + 64);    // prefetch next chunk

        // S = Q·K^T : 16 rows x 64 cols per wave
        f32x4 acc_s[4] = {};
        #pragma unroll
        for (int ks = 0; ks < 4; ++ks) {
            #pragma unroll
            for (int n16 = 0; n16 < 4; ++n16) {
                bf16x8 bk = *(const bf16x8*)&Ks[n16 * 16 + L15][ks * 32 + quad * 8];
                acc_s[n16] = __builtin_amdgcn_mfma_f32_16x16x32_bf16(qf[ks], bk, acc_s[n16], 0, 0, 0);
            }
        }

        // mask + RPE + online softmax (C-layout: row=quad*4+r, col=n16*16+L15)
        #pragma unroll
        for (int r = 0; r < 4; ++r) {
            const int ig = i0 + 16 * w + quad * 4 + r;
            float sv[4];
            #pragma unroll
            for (int n16 = 0; n16 < 4; ++n16) {
                const int d = ig - (j0 + n16 * 16 + L15);
                const int ix = min(max(d - 1, 0), 511);
                sv[n16] = (d >= 1 && d <= 511) ? (acc_s[n16][r] * scale + embs[ix])
                                               : -1e30f;
            }
            float mx = fmaxf(fmaxf(sv[0], sv[1]), fmaxf(sv[2], sv[3]));
            mx = fmaxf(mx, __shfl_xor(mx, 1));
            mx = fmaxf(mx, __shfl_xor(mx, 2));
            mx = fmaxf(mx, __shfl_xor(mx, 4));
            mx = fmaxf(mx, __shfl_xor(mx, 8));
            const float mnew  = fmaxf(m_r[r], mx);
            const float alpha = __expf(m_r[r] - mnew);
            m_r[r] = mnew;
            float p[4], rs = 0.f;
            #pragma unroll
            for (int n16 = 0; n16 < 4; ++n16) {
                p[n16] = (sv[n16] > -1e29f) ? __expf(sv[n16] - mnew) : 0.f;
                rs += p[n16];
            }
            rs += __shfl_xor(rs, 1);
            rs += __shfl_xor(rs, 2);
            rs += __shfl_xor(rs, 4);
            rs += __shfl_xor(rs, 8);
            l_r[r] = l_r[r] * alpha + rs;
            #pragma unroll
            for (int nt = 0; nt < 8; ++nt) acc_o[nt][r] *= alpha;
            #pragma unroll
            for (int n16 = 0; n16 < 4; ++n16)
                Ps[16 * w + quad * 4 + r][n16 * 16 + L15] = f2bf(p[n16]);
        }
        __syncthreads();   // Ps C->A layout hand-off

        // O += P·V  (k-dim 64 -> 2 A-frags)
        #pragma unroll
        for (int ks = 0; ks < 2; ++ks) {
            bf16x8 ap = *(const bf16x8*)&Ps[16 * w + L15][ks * 32 + quad * 8];
            #pragma unroll
            for (int nt = 0; nt < 8; ++nt) {
                bf16x8 bv = *(const bf16x8*)&Vt[nt * 16 + L15][ks * 32 + quad * 8];
                acc_o[nt] = __builtin_amdgcn_mfma_f32_16x16x32_bf16(ap, bv, acc_o[nt], 0, 0, 0);
            }
        }
    }

    // epilogue (fp32 out): out[b, ig, h*128 + d] = acc / l ; row 0 -> V[:,0]
    #pragma unroll
    for (int r = 0; r < 4; ++r) {
        const int ig = i0 + 16 * w + quad * 4 + r;
        float* o = out + ((size_t)(b * Ssz + ig)) * HDp + h * Dd;
        if (ig == 0) {
            #pragma unroll
            for (int nt = 0; nt < 8; ++nt)
                o[nt * 16 + L15] = bflo((u32)Vh[(size_t)(nt * 16 + L15) * Ssz]);
        } else {
            const float inv = 1.0f / l_r[r];
            #pragma unroll
            for (int nt = 0; nt < 8; ++nt)
                o[nt * 16 + L15] = acc_o[nt][r] * inv;
        }
    }
}

extern "C" void kernel_launch(void* const* d_in, const int* in_sizes, int n_in,
                              void* d_out, int out_size, void* d_ws, size_t ws_size,
                              hipStream_t stream)
{
    const float* q   = (const float*)d_in[0];
    const float* k   = (const float*)d_in[1];
    const float* v   = (const float*)d_in[2];
    const float* Wq  = (const float*)d_in[3];
    const float* Wk  = (const float*)d_in[4];
    const float* Wv  = (const float*)d_in[5];
    const float* emb = (const float*)d_in[6];
    float* out = (float*)d_out;

    // ws: [0,768KB) W^T bf16 x3 | [1MB, ...) Qp/Kp/VpT bf16
    u16* Wtp = (u16*)d_ws;
    const size_t per = (size_t)Bb * Hh * Ssz * Dd;
    u16* Qp  = (u16*)((char*)d_ws + (1 << 20));
    u16* Kp  = Qp + per;
    u16* VpT = Kp + per;

    dim3 blk(256);
    wprep_kernel<<<dim3(16, 3), blk, 0, stream>>>(Wq, Wk, Wv, Wtp);
    proj_kernel<<<dim3(64, 48), blk, 0, stream>>>(q, k, v, Wtp, Qp, Kp, VpT);
    attn_kernel<<<dim3(512), blk, 0, stream>>>(Qp, Kp, VpT, emb, out);
}